// Round 4
// baseline (153.404 us; speedup 1.0000x reference)
//
#include <hip/hip_runtime.h>
#include <stdint.h>

#define HEADS 12
#define DH 64
#define SEQ 1024
#define BATCH 2
#define DIMC 768
#define MROWS (BATCH*SEQ)   // 2048
#define NQKV (3*DIMC)       // 2304

typedef __bf16 bf16x8 __attribute__((ext_vector_type(8)));
typedef float f32x4 __attribute__((ext_vector_type(4)));
typedef unsigned int u32x4 __attribute__((ext_vector_type(4)));

__device__ __forceinline__ uint16_t f2bf(float f) {
  uint32_t u = __builtin_bit_cast(uint32_t, f);
  uint32_t r = (u + 0x7fffu + ((u >> 16) & 1u)) >> 16;
  return (uint16_t)r;
}
__device__ __forceinline__ float bf2f(uint16_t h) {
  uint32_t u = ((uint32_t)h) << 16;
  return __builtin_bit_cast(float, u);
}

// async global -> LDS, 16 B per lane (wave writes base + lane*16)
__device__ __forceinline__ void gl16(const void* g, void* l) {
  __builtin_amdgcn_global_load_lds(
      (const __attribute__((address_space(1))) void*)g,
      (__attribute__((address_space(3))) void*)l, 16, 0, 0);
}

// ---------------- prep: split x into bf16 hi/lo ----------------
__global__ __launch_bounds__(256) void k_split_x(
    const float* __restrict__ x1, const float* __restrict__ x2,
    uint16_t* __restrict__ xh, uint16_t* __restrict__ xl) {
  int i = blockIdx.x * 256 + threadIdx.x;   // float4 index
  const int per = MROWS * DIMC / 4;         // 393216 per stream
  const float* src = (i < per) ? x1 : x2;
  int j = (i < per) ? i : (i - per);
  float4 v = reinterpret_cast<const float4*>(src)[j];
  float f[4] = {v.x, v.y, v.z, v.w};
  uint16_t hh[4], ll[4];
#pragma unroll
  for (int t = 0; t < 4; ++t) {
    hh[t] = f2bf(f[t]);
    ll[t] = f2bf(f[t] - bf2f(hh[t]));
  }
  reinterpret_cast<ushort4*>(xh)[i] = make_ushort4(hh[0], hh[1], hh[2], hh[3]);
  reinterpret_cast<ushort4*>(xl)[i] = make_ushort4(ll[0], ll[1], ll[2], ll[3]);
}

// ---------------- prep: transpose f32 [R][C] -> bf16 [C][R] ----------------
__global__ __launch_bounds__(256) void k_transpose_bf16(
    const float* __restrict__ src, uint16_t* __restrict__ dst, int R, int C) {
  __shared__ uint16_t tile[32][33];
  int c0 = blockIdx.x * 32, r0 = blockIdx.y * 32;
  int tx = threadIdx.x, ty = threadIdx.y;
  for (int rr = ty; rr < 32; rr += 8)
    tile[rr][tx] = f2bf(src[(size_t)(r0 + rr) * C + c0 + tx]);
  __syncthreads();
  for (int rr = ty; rr < 32; rr += 8)
    dst[(size_t)(c0 + rr) * R + r0 + tx] = tile[tx][rr];
}

// ---------------- QKV GEMM v2: 128x128 tile, BK=32, global_load_lds ----------------
// LDS chunk-swizzle: stored chunk position p holds original chunk p ^ ((row>>1)&3);
// achieved by pre-swizzling the global source chunk (linear LDS dest, rule #21).
__global__ __launch_bounds__(256) void k_qkv_gemm(
    const uint16_t* __restrict__ xh, const uint16_t* __restrict__ xl,
    const uint16_t* __restrict__ wt,   // [2][2304][768] (W transposed)
    uint16_t* __restrict__ qo, uint16_t* __restrict__ ko, uint16_t* __restrict__ vto) {
  __shared__ __align__(16) uint16_t Ah[128][32];
  __shared__ __align__(16) uint16_t Al[128][32];
  __shared__ __align__(16) uint16_t Bt[128][32];
  const int s = blockIdx.z;
  const int m0 = blockIdx.x * 128;
  const int col0 = blockIdx.y * 128;
  const uint16_t* xh_s = xh + (size_t)s * MROWS * DIMC;
  const uint16_t* xl_s = xl + (size_t)s * MROWS * DIMC;
  const uint16_t* wt_s = wt + (size_t)s * NQKV * DIMC;

  const int tid = threadIdx.x;
  const int w = tid >> 6, lane = tid & 63;
  const int wm = w >> 1, wn = w & 1;
  const int lr = lane & 15, g = lane >> 4;
  const int pc = (g ^ ((lr >> 1) & 3)) * 8;                   // swizzled frag chunk
  const int srow = lane >> 2;                                 // 0..15 within issue
  const int schunk = ((lane & 3) ^ ((lane >> 3) & 3)) * 8;    // swizzled source chunk

  f32x4 acc[4][4] = {};

  const size_t aoff0 = (size_t)(m0 + w * 32 + srow) * DIMC + schunk;
  const size_t aoff1 = (size_t)(m0 + w * 32 + 16 + srow) * DIMC + schunk;
  const size_t boff0 = (size_t)(col0 + w * 32 + srow) * DIMC + schunk;
  const size_t boff1 = (size_t)(col0 + w * 32 + 16 + srow) * DIMC + schunk;

  for (int k0 = 0; k0 < DIMC; k0 += 32) {
    gl16(xh_s + aoff0 + k0, &Ah[w * 32][0]);
    gl16(xh_s + aoff1 + k0, &Ah[w * 32 + 16][0]);
    gl16(xl_s + aoff0 + k0, &Al[w * 32][0]);
    gl16(xl_s + aoff1 + k0, &Al[w * 32 + 16][0]);
    gl16(wt_s + boff0 + k0, &Bt[w * 32][0]);
    gl16(wt_s + boff1 + k0, &Bt[w * 32 + 16][0]);
    __syncthreads();   // vmcnt(0) drain + barrier: tile visible to all waves

    bf16x8 ah[4], al[4], bb[4];
#pragma unroll
    for (int f = 0; f < 4; ++f) {
      ah[f] = *reinterpret_cast<const bf16x8*>(&Ah[wm * 64 + f * 16 + lr][pc]);
      al[f] = *reinterpret_cast<const bf16x8*>(&Al[wm * 64 + f * 16 + lr][pc]);
      bb[f] = *reinterpret_cast<const bf16x8*>(&Bt[wn * 64 + f * 16 + lr][pc]);
    }
#pragma unroll
    for (int fm = 0; fm < 4; ++fm)
#pragma unroll
      for (int fn = 0; fn < 4; ++fn) {
        acc[fm][fn] = __builtin_amdgcn_mfma_f32_16x16x32_bf16(ah[fm], bb[fn], acc[fm][fn], 0, 0, 0);
        acc[fm][fn] = __builtin_amdgcn_mfma_f32_16x16x32_bf16(al[fm], bb[fn], acc[fm][fn], 0, 0, 0);
      }
    __syncthreads();   // reads done before next tile overwrites
  }

  const int t = col0 / 768;       // tiles never straddle the q/k/v boundary
  const int cbase = col0 % 768;
  uint16_t* q_s  = qo  + (size_t)s * 1572864;
  uint16_t* k_s  = ko  + (size_t)s * 1572864;
  uint16_t* vt_s = vto + (size_t)s * 1572864;
#pragma unroll
  for (int fm = 0; fm < 4; ++fm)
#pragma unroll
    for (int fn = 0; fn < 4; ++fn) {
      const int col_in = cbase + wn * 64 + fn * 16 + lr;
      const int h = col_in >> 6, dh = col_in & 63;
#pragma unroll
      for (int i = 0; i < 4; ++i) {
        int m = m0 + wm * 64 + fm * 16 + g * 4 + i;
        int b_ = m >> 10, n = m & 1023;
        float v = acc[fm][fn][i];
        if (t == 0)
          q_s[((size_t)(b_ * HEADS + h) * SEQ + n) * DH + dh] = f2bf(v * 0.125f);
        else if (t == 1)
          k_s[((size_t)(b_ * HEADS + h) * SEQ + n) * DH + dh] = f2bf(v);
        else
          vt_s[((size_t)(b_ * HEADS + h) * DH + dh) * SEQ + n] = f2bf(v);
      }
    }
}

// ---------------- fused dual-pass flash attention (swapped QK^T) ----------------
__global__ __launch_bounds__(256) void k_attn(
    const uint16_t* __restrict__ q, const uint16_t* __restrict__ k,
    const uint16_t* __restrict__ vt, uint16_t* __restrict__ o) {
  __shared__ uint16_t Klds[64][64];   // [key][dh], col chunks XOR-swizzled by row&7
  __shared__ uint16_t Vlds[64][64];   // [dh][key], col chunks XOR-swizzled by row&7

  int bid = blockIdx.x;
  bid = (bid & 7) * 96 + (bid >> 3);
  const int qt = bid & 15;
  int rest = bid >> 4;            // 0..47
  const int h = rest % 12;
  int rest2 = rest / 12;          // 0..3
  const int b = rest2 & 1;
  const int s = rest2 >> 1;

  const int tid = threadIdx.x;
  const int w = tid >> 6, lane = tid & 63;
  const int lr = lane & 15;
  const int g = lane >> 4;        // 0..3
  const int hi8 = g * 8;

  const uint16_t* q_s = q + (size_t)s * 1572864 +
                        ((size_t)(b * HEADS + h) * SEQ + qt * 64 + w * 16 + lr) * DH;
  const bf16x8 qf0 = *reinterpret_cast<const bf16x8*>(&q_s[hi8]);
  const bf16x8 qf1 = *reinterpret_cast<const bf16x8*>(&q_s[32 + hi8]);

  const int klo = (lr >> 2) * 8 + (lr & 3);

  const int r0 = tid >> 3;                 // 0..31 (and r0+32)
  const int c0 = tid & 7;
  const int swc = 8 * (c0 ^ (r0 & 7));     // (r0+32)&7 == r0&7

  const uint16_t* kbase0 = k  + (size_t)s * 1572864 + (size_t)(b * HEADS + h) * SEQ * DH;
  const uint16_t* vbase0 = vt + (size_t)s * 1572864 + (size_t)(b * HEADS + h) * DH * SEQ;
  const uint16_t* kbase1 = k  + (size_t)(1 - s) * 1572864 + (size_t)(b * HEADS + h) * SEQ * DH;
  const uint16_t* vbase1 = vt + (size_t)(1 - s) * 1572864 + (size_t)(b * HEADS + h) * DH * SEQ;

  u32x4 kr0, kr1, vr0, vr1;

#define LOADT(T) { const int tt = (T); const int kt_ = tt & 15;                             \
    const uint16_t* kp = (tt >= 16) ? kbase1 : kbase0;                                      \
    const uint16_t* vp = (tt >= 16) ? vbase1 : vbase0;                                      \
    kr0 = *reinterpret_cast<const u32x4*>(&kp[(size_t)(kt_ * 64 + r0) * DH + c0 * 8]);      \
    kr1 = *reinterpret_cast<const u32x4*>(&kp[(size_t)(kt_ * 64 + r0 + 32) * DH + c0 * 8]); \
    vr0 = *reinterpret_cast<const u32x4*>(&vp[(size_t)r0 * SEQ + kt_ * 64 + c0 * 8]);       \
    vr1 = *reinterpret_cast<const u32x4*>(&vp[(size_t)(r0 + 32) * SEQ + kt_ * 64 + c0 * 8]); }

#define STORET() {                                            \
    *reinterpret_cast<u32x4*>(&Klds[r0][swc]) = kr0;          \
    *reinterpret_cast<u32x4*>(&Klds[r0 + 32][swc]) = kr1;     \
    *reinterpret_cast<u32x4*>(&Vlds[r0][swc]) = vr0;          \
    *reinterpret_cast<u32x4*>(&Vlds[r0 + 32][swc]) = vr1; }

  LOADT(0);
  STORET();
  __syncthreads();

  f32x4 Oacc[4] = {};
  f32x4 Ofin[4] = {};
  float mrow = -1e30f, lrow = 0.f;

  for (int t = 0; t < 32; ++t) {
    if (t < 31) LOADT(t + 1);

    f32x4 S[4];
#pragma unroll
    for (int fn = 0; fn < 4; ++fn) {
      const int krow = klo + 4 * (fn & 1) + 32 * (fn >> 1);
      const int sw = krow & 7;
      bf16x8 ka = *reinterpret_cast<const bf16x8*>(&Klds[krow][8 * (g ^ sw)]);
      bf16x8 kb = *reinterpret_cast<const bf16x8*>(&Klds[krow][8 * ((4 + g) ^ sw)]);
      f32x4 z = {};
      z = __builtin_amdgcn_mfma_f32_16x16x32_bf16(ka, qf0, z, 0, 0, 0);
      S[fn] = __builtin_amdgcn_mfma_f32_16x16x32_bf16(kb, qf1, z, 0, 0, 0);
    }

    float vmax = fmaxf(fmaxf(fmaxf(S[0][0], S[0][1]), fmaxf(S[0][2], S[0][3])),
                       fmaxf(fmaxf(S[1][0], S[1][1]), fmaxf(S[1][2], S[1][3])));
    vmax = fmaxf(vmax, fmaxf(fmaxf(fmaxf(S[2][0], S[2][1]), fmaxf(S[2][2], S[2][3])),
                             fmaxf(fmaxf(S[3][0], S[3][1]), fmaxf(S[3][2], S[3][3]))));
    vmax = fmaxf(vmax, __shfl_xor(vmax, 16));
    vmax = fmaxf(vmax, __shfl_xor(vmax, 32));
    const float mnew = fmaxf(mrow, vmax);
    const float alpha = __expf(mrow - mnew);
    mrow = mnew;
    float rs = 0.f;
#pragma unroll
    for (int fn = 0; fn < 4; ++fn)
#pragma unroll
      for (int i = 0; i < 4; ++i) {
        float p = __expf(S[fn][i] - mnew);
        S[fn][i] = p;
        rs += p;
      }
    rs += __shfl_xor(rs, 16);
    rs += __shfl_xor(rs, 32);
    lrow = lrow * alpha + rs;

    bf16x8 pa0, pa1;
#pragma unroll
    for (int i = 0; i < 4; ++i) {
      pa0[i]     = (__bf16)S[0][i];
      pa0[4 + i] = (__bf16)S[1][i];
      pa1[i]     = (__bf16)S[2][i];
      pa1[4 + i] = (__bf16)S[3][i];
    }

    float af[4];
#pragma unroll
    for (int i = 0; i < 4; ++i) af[i] = __shfl(alpha, 20 * g + i);
#pragma unroll
    for (int fn = 0; fn < 4; ++fn)
#pragma unroll
      for (int i = 0; i < 4; ++i) Oacc[fn][i] *= af[i];

#pragma unroll
    for (int fn = 0; fn < 4; ++fn) {
      const int vrow = fn * 16 + lr;
      const int sw = vrow & 7;
      bf16x8 va = *reinterpret_cast<const bf16x8*>(&Vlds[vrow][8 * (g ^ sw)]);
      bf16x8 vb = *reinterpret_cast<const bf16x8*>(&Vlds[vrow][8 * ((4 + g) ^ sw)]);
      Oacc[fn] = __builtin_amdgcn_mfma_f32_16x16x32_bf16(pa0, va, Oacc[fn], 0, 0, 0);
      Oacc[fn] = __builtin_amdgcn_mfma_f32_16x16x32_bf16(pa1, vb, Oacc[fn], 0, 0, 0);
    }

    if (t == 15 || t == 31) {
      const float linv = 1.f / lrow;
      float li[4];
#pragma unroll
      for (int i = 0; i < 4; ++i) li[i] = __shfl(linv, 20 * g + i);
#pragma unroll
      for (int fn = 0; fn < 4; ++fn)
#pragma unroll
        for (int i = 0; i < 4; ++i) Ofin[fn][i] += Oacc[fn][i] * li[i];
      if (t == 15) {
        mrow = -1e30f; lrow = 0.f;
#pragma unroll
        for (int fn = 0; fn < 4; ++fn) Oacc[fn] = f32x4{};
      }
    }

    __syncthreads();
    if (t < 31) {
      STORET();
      __syncthreads();
    }
  }
#undef LOADT
#undef STORET

  uint16_t* o_s = o + (size_t)s * MROWS * DIMC;
#pragma unroll
  for (int fn = 0; fn < 4; ++fn)
#pragma unroll
    for (int i = 0; i < 4; ++i) {
      int n = qt * 64 + w * 16 + g * 4 + i;
      int col = h * 64 + fn * 16 + lr;
      o_s[(size_t)(b * SEQ + n) * DIMC + col] = f2bf(Ofin[fn][i]);
    }
}

// ---------------- projection GEMM v2: 128x128 tile, global_load_lds ----------------
__global__ __launch_bounds__(256) void k_proj_gemm(
    const uint16_t* __restrict__ o, const uint16_t* __restrict__ wpt,
    const float* __restrict__ bp1, const float* __restrict__ bp2,
    float* __restrict__ out) {
  __shared__ __align__(16) uint16_t At[128][32];
  __shared__ __align__(16) uint16_t Bt[128][32];
  const int s = blockIdx.z;
  const int m0 = blockIdx.x * 128;
  const int col0 = blockIdx.y * 128;
  const uint16_t* o_s = o + (size_t)s * MROWS * DIMC;
  const uint16_t* w_s = wpt + (size_t)s * DIMC * DIMC;
  const float* bias = (s == 0) ? bp1 : bp2;
  float* out_s = out + (size_t)s * MROWS * DIMC;

  const int tid = threadIdx.x;
  const int w = tid >> 6, lane = tid & 63;
  const int wm = w >> 1, wn = w & 1;
  const int lr = lane & 15, g = lane >> 4;
  const int pc = (g ^ ((lr >> 1) & 3)) * 8;
  const int srow = lane >> 2;
  const int schunk = ((lane & 3) ^ ((lane >> 3) & 3)) * 8;

  f32x4 acc[4][4] = {};

  const size_t aoff0 = (size_t)(m0 + w * 32 + srow) * DIMC + schunk;
  const size_t aoff1 = (size_t)(m0 + w * 32 + 16 + srow) * DIMC + schunk;
  const size_t boff0 = (size_t)(col0 + w * 32 + srow) * DIMC + schunk;
  const size_t boff1 = (size_t)(col0 + w * 32 + 16 + srow) * DIMC + schunk;

  for (int k0 = 0; k0 < DIMC; k0 += 32) {
    gl16(o_s + aoff0 + k0, &At[w * 32][0]);
    gl16(o_s + aoff1 + k0, &At[w * 32 + 16][0]);
    gl16(w_s + boff0 + k0, &Bt[w * 32][0]);
    gl16(w_s + boff1 + k0, &Bt[w * 32 + 16][0]);
    __syncthreads();

    bf16x8 a[4], bb[4];
#pragma unroll
    for (int f = 0; f < 4; ++f) {
      a[f]  = *reinterpret_cast<const bf16x8*>(&At[wm * 64 + f * 16 + lr][pc]);
      bb[f] = *reinterpret_cast<const bf16x8*>(&Bt[wn * 64 + f * 16 + lr][pc]);
    }
#pragma unroll
    for (int fm = 0; fm < 4; ++fm)
#pragma unroll
      for (int fn = 0; fn < 4; ++fn)
        acc[fm][fn] = __builtin_amdgcn_mfma_f32_16x16x32_bf16(a[fm], bb[fn], acc[fm][fn], 0, 0, 0);
    __syncthreads();
  }

#pragma unroll
  for (int fm = 0; fm < 4; ++fm)
#pragma unroll
    for (int fn = 0; fn < 4; ++fn) {
      const int col = col0 + wn * 64 + fn * 16 + lr;
      const float bv = bias[col];
#pragma unroll
      for (int i = 0; i < 4; ++i) {
        int m = m0 + wm * 64 + fm * 16 + g * 4 + i;
        out_s[(size_t)m * DIMC + col] = acc[fm][fn][i] + bv;
      }
    }
}

extern "C" void kernel_launch(void* const* d_in, const int* in_sizes, int n_in,
                              void* d_out, int out_size, void* d_ws, size_t ws_size,
                              hipStream_t stream) {
  const float* x1    = (const float*)d_in[0];
  const float* x2    = (const float*)d_in[1];
  const float* Wqkv1 = (const float*)d_in[2];
  const float* Wqkv2 = (const float*)d_in[3];
  const float* Wp1   = (const float*)d_in[4];
  const float* bp1   = (const float*)d_in[5];
  const float* Wp2   = (const float*)d_in[6];
  const float* bp2   = (const float*)d_in[7];
  float* out = (float*)d_out;

  uint8_t* ws = (uint8_t*)d_ws;
  uint16_t* xh    = (uint16_t*)(ws);             // 2*2048*768 bf16 = 6291456 B
  uint16_t* xl    = (uint16_t*)(ws + 6291456);
  uint16_t* wqkvt = (uint16_t*)(ws + 12582912);  // 2*2304*768 = 7077888 B
  uint16_t* wpt   = (uint16_t*)(ws + 19660800);  // 2*768*768  = 2359296 B
  uint16_t* qb    = (uint16_t*)(ws + 22020096);  // 2*1572864  = 6291456 B
  uint16_t* kb    = (uint16_t*)(ws + 28311552);
  uint16_t* vtb   = (uint16_t*)(ws + 34603008);
  uint16_t* ob    = (uint16_t*)(ws + 40894464);  // total 47185920 B

  k_split_x<<<3072, 256, 0, stream>>>(x1, x2, xh, xl);
  k_transpose_bf16<<<dim3(72, 24), dim3(32, 8), 0, stream>>>(Wqkv1, wqkvt, 768, 2304);
  k_transpose_bf16<<<dim3(72, 24), dim3(32, 8), 0, stream>>>(Wqkv2, wqkvt + 2304 * 768, 768, 2304);
  k_transpose_bf16<<<dim3(24, 24), dim3(32, 8), 0, stream>>>(Wp1, wpt, 768, 768);
  k_transpose_bf16<<<dim3(24, 24), dim3(32, 8), 0, stream>>>(Wp2, wpt + 768 * 768, 768, 768);
  k_qkv_gemm<<<dim3(16, 18, 2), 256, 0, stream>>>(xh, xl, wqkvt, qb, kb, vtb);
  k_attn<<<768, 256, 0, stream>>>(qb, kb, vtb, ob);
  k_proj_gemm<<<dim3(16, 6, 2), 256, 0, stream>>>(ob, wpt, bp1, bp2, out);
}

// Round 5
// 147.708 us; speedup vs baseline: 1.0386x; 1.0386x over previous
//
#include <hip/hip_runtime.h>
#include <stdint.h>

#define HEADS 12
#define DH 64
#define SEQ 1024
#define BATCH 2
#define DIMC 768
#define MROWS (BATCH*SEQ)   // 2048
#define NQKV (3*DIMC)       // 2304

typedef __bf16 bf16x8 __attribute__((ext_vector_type(8)));
typedef float f32x4 __attribute__((ext_vector_type(4)));
typedef unsigned int u32x4 __attribute__((ext_vector_type(4)));

__device__ __forceinline__ uint16_t f2bf(float f) {
  uint32_t u = __builtin_bit_cast(uint32_t, f);
  uint32_t r = (u + 0x7fffu + ((u >> 16) & 1u)) >> 16;
  return (uint16_t)r;
}
__device__ __forceinline__ float bf2f(uint16_t h) {
  uint32_t u = ((uint32_t)h) << 16;
  return __builtin_bit_cast(float, u);
}

// async global -> LDS, 16 B per lane (wave writes base + lane*16)
__device__ __forceinline__ void gl16(const void* g, void* l) {
  __builtin_amdgcn_global_load_lds(
      (const __attribute__((address_space(1))) void*)g,
      (__attribute__((address_space(3))) void*)l, 16, 0, 0);
}

// ---------------- prep: split x into bf16 hi/lo ----------------
__global__ __launch_bounds__(256) void k_split_x(
    const float* __restrict__ x1, const float* __restrict__ x2,
    uint16_t* __restrict__ xh, uint16_t* __restrict__ xl) {
  int i = blockIdx.x * 256 + threadIdx.x;   // float4 index
  const int per = MROWS * DIMC / 4;         // 393216 per stream
  const float* src = (i < per) ? x1 : x2;
  int j = (i < per) ? i : (i - per);
  float4 v = reinterpret_cast<const float4*>(src)[j];
  float f[4] = {v.x, v.y, v.z, v.w};
  uint16_t hh[4], ll[4];
#pragma unroll
  for (int t = 0; t < 4; ++t) {
    hh[t] = f2bf(f[t]);
    ll[t] = f2bf(f[t] - bf2f(hh[t]));
  }
  reinterpret_cast<ushort4*>(xh)[i] = make_ushort4(hh[0], hh[1], hh[2], hh[3]);
  reinterpret_cast<ushort4*>(xl)[i] = make_ushort4(ll[0], ll[1], ll[2], ll[3]);
}

// ---------------- prep: all four weight transposes in one launch ----------------
__global__ __launch_bounds__(256) void k_transpose_all(
    const float* __restrict__ Wqkv1, const float* __restrict__ Wqkv2,
    const float* __restrict__ Wp1, const float* __restrict__ Wp2,
    uint16_t* __restrict__ wqkvt, uint16_t* __restrict__ wpt) {
  __shared__ uint16_t tile[32][33];
  int id = blockIdx.x;
  const float* src; uint16_t* dst; int C, xo, yo;
  if (id < 3456) {                 // 2 x (72*24) tiles for Wqkv
    int s = id / 1728; id %= 1728;
    src = s ? Wqkv2 : Wqkv1; dst = wqkvt + (size_t)s * NQKV * DIMC; C = NQKV;
    xo = id % 72; yo = id / 72;
  } else {                         // 2 x (24*24) tiles for Wp
    id -= 3456; int s = id / 576; id %= 576;
    src = s ? Wp2 : Wp1; dst = wpt + (size_t)s * DIMC * DIMC; C = DIMC;
    xo = id % 24; yo = id / 24;
  }
  const int R = DIMC;
  int c0 = xo * 32, r0 = yo * 32;
  int tx = threadIdx.x, ty = threadIdx.y;
  for (int rr = ty; rr < 32; rr += 8)
    tile[rr][tx] = f2bf(src[(size_t)(r0 + rr) * C + c0 + tx]);
  __syncthreads();
  for (int rr = ty; rr < 32; rr += 8)
    dst[(size_t)(c0 + rr) * R + r0 + tx] = tile[tx][rr];
}

// ---------------- QKV GEMM v3: 128x64 tile, 2-phase dbuf pipeline ----------------
__global__ __launch_bounds__(256) void k_qkv_gemm(
    const uint16_t* __restrict__ xh, const uint16_t* __restrict__ xl,
    const uint16_t* __restrict__ wt,   // [2][2304][768] (W transposed)
    uint16_t* __restrict__ qo, uint16_t* __restrict__ ko, uint16_t* __restrict__ vto) {
  __shared__ __align__(16) uint16_t Ah[2][128][32];
  __shared__ __align__(16) uint16_t Al[2][128][32];
  __shared__ __align__(16) uint16_t Bt[2][64][32];

  // bijective XCD remap, y-fastest per XCD (A 1.5MB + B 3.4MB ~ L2-resident)
  int flat = blockIdx.x + 16 * blockIdx.y + 576 * blockIdx.z;   // 1152 blocks
  flat = (flat & 7) * 144 + (flat >> 3);
  const int yb = flat % 36;
  const int xb = (flat / 36) % 16;
  const int s  = flat / 576;
  const int m0 = xb * 128;
  const int col0 = yb * 64;

  const uint16_t* xh_s = xh + (size_t)s * MROWS * DIMC;
  const uint16_t* xl_s = xl + (size_t)s * MROWS * DIMC;
  const uint16_t* wt_s = wt + (size_t)s * NQKV * DIMC;

  const int tid = threadIdx.x;
  const int w = tid >> 6, lane = tid & 63;
  const int lr = lane & 15, g = lane >> 4;
  const int pc = (g ^ ((lr >> 1) & 3)) * 8;                   // swizzled frag chunk
  const int srow = lane >> 2;                                 // 0..15
  const int schunk = ((lane & 3) ^ ((lane >> 3) & 3)) * 8;    // swizzled source chunk

  f32x4 acc[2][4] = {};

  const size_t aoff0 = (size_t)(m0 + w * 32 + srow) * DIMC + schunk;
  const size_t aoff1 = (size_t)(m0 + w * 32 + 16 + srow) * DIMC + schunk;
  const size_t boff  = (size_t)(col0 + w * 16 + srow) * DIMC + schunk;

#define STAGE(B, K0) do {                                      \
    gl16(xh_s + aoff0 + (K0), &Ah[B][w * 32][0]);              \
    gl16(xh_s + aoff1 + (K0), &Ah[B][w * 32 + 16][0]);         \
    gl16(xl_s + aoff0 + (K0), &Al[B][w * 32][0]);              \
    gl16(xl_s + aoff1 + (K0), &Al[B][w * 32 + 16][0]);         \
    gl16(wt_s + boff  + (K0), &Bt[B][w * 16][0]); } while (0)

  STAGE(0, 0);
  asm volatile("s_waitcnt vmcnt(0)" ::: "memory");
  __builtin_amdgcn_s_barrier();

  for (int kt = 0; kt < 24; ++kt) {
    const int cur = kt & 1;
    if (kt < 23) STAGE(cur ^ 1, (kt + 1) * 32);

    bf16x8 ah[2], al[2], bb[4];
#pragma unroll
    for (int f = 0; f < 2; ++f) {
      ah[f] = *reinterpret_cast<const bf16x8*>(&Ah[cur][w * 32 + f * 16 + lr][pc]);
      al[f] = *reinterpret_cast<const bf16x8*>(&Al[cur][w * 32 + f * 16 + lr][pc]);
    }
#pragma unroll
    for (int f = 0; f < 4; ++f)
      bb[f] = *reinterpret_cast<const bf16x8*>(&Bt[cur][f * 16 + lr][pc]);

    asm volatile("s_waitcnt lgkmcnt(0)" ::: "memory");
    __builtin_amdgcn_sched_barrier(0);
    __builtin_amdgcn_s_setprio(1);
#pragma unroll
    for (int fm = 0; fm < 2; ++fm)
#pragma unroll
      for (int fn = 0; fn < 4; ++fn) {
        acc[fm][fn] = __builtin_amdgcn_mfma_f32_16x16x32_bf16(ah[fm], bb[fn], acc[fm][fn], 0, 0, 0);
        acc[fm][fn] = __builtin_amdgcn_mfma_f32_16x16x32_bf16(al[fm], bb[fn], acc[fm][fn], 0, 0, 0);
      }
    __builtin_amdgcn_s_setprio(0);

    asm volatile("s_waitcnt vmcnt(0)" ::: "memory");
    __builtin_amdgcn_s_barrier();
  }
#undef STAGE

  const int t = col0 / 768;       // 64 | 768: tiles never straddle q/k/v
  const int cbase = col0 % 768;
  const int h = cbase >> 6;       // one head per 64-col tile
  uint16_t* q_s  = qo  + (size_t)s * 1572864;
  uint16_t* k_s  = ko  + (size_t)s * 1572864;
  uint16_t* vt_s = vto + (size_t)s * 1572864;
#pragma unroll
  for (int fm = 0; fm < 2; ++fm)
#pragma unroll
    for (int fn = 0; fn < 4; ++fn) {
      const int dh = fn * 16 + lr;
#pragma unroll
      for (int i = 0; i < 4; ++i) {
        int m = m0 + w * 32 + fm * 16 + g * 4 + i;
        int b_ = m >> 10, n = m & 1023;
        float v = acc[fm][fn][i];
        if (t == 0)
          q_s[((size_t)(b_ * HEADS + h) * SEQ + n) * DH + dh] = f2bf(v * 0.125f);
        else if (t == 1)
          k_s[((size_t)(b_ * HEADS + h) * SEQ + n) * DH + dh] = f2bf(v);
        else
          vt_s[((size_t)(b_ * HEADS + h) * DH + dh) * SEQ + n] = f2bf(v);
      }
    }
}

// ---------------- fused dual-pass flash attention (swapped QK^T, dbuf) ----------------
__global__ __launch_bounds__(256) void k_attn(
    const uint16_t* __restrict__ q, const uint16_t* __restrict__ k,
    const uint16_t* __restrict__ vt, uint16_t* __restrict__ o) {
  __shared__ uint16_t Klds[2][64][64];   // [key][dh], chunks XOR-swizzled by row&7
  __shared__ uint16_t Vlds[2][64][64];   // [dh][key], chunks XOR-swizzled by row&7

  int bid = blockIdx.x;
  bid = (bid & 7) * 96 + (bid >> 3);
  const int qt = bid & 15;
  int rest = bid >> 4;            // 0..47
  const int h = rest % 12;
  int rest2 = rest / 12;          // 0..3
  const int b = rest2 & 1;
  const int s = rest2 >> 1;

  const int tid = threadIdx.x;
  const int w = tid >> 6, lane = tid & 63;
  const int lr = lane & 15;
  const int g = lane >> 4;        // 0..3
  const int hi8 = g * 8;

  const uint16_t* q_s = q + (size_t)s * 1572864 +
                        ((size_t)(b * HEADS + h) * SEQ + qt * 64 + w * 16 + lr) * DH;
  const bf16x8 qf0 = *reinterpret_cast<const bf16x8*>(&q_s[hi8]);
  const bf16x8 qf1 = *reinterpret_cast<const bf16x8*>(&q_s[32 + hi8]);

  const int klo = (lr >> 2) * 8 + (lr & 3);

  const int r0 = tid >> 3;                 // 0..31 (and r0+32)
  const int c0 = tid & 7;
  const int swc = 8 * (c0 ^ (r0 & 7));     // (r0+32)&7 == r0&7

  const uint16_t* kbase0 = k  + (size_t)s * 1572864 + (size_t)(b * HEADS + h) * SEQ * DH;
  const uint16_t* vbase0 = vt + (size_t)s * 1572864 + (size_t)(b * HEADS + h) * DH * SEQ;
  const uint16_t* kbase1 = k  + (size_t)(1 - s) * 1572864 + (size_t)(b * HEADS + h) * SEQ * DH;
  const uint16_t* vbase1 = vt + (size_t)(1 - s) * 1572864 + (size_t)(b * HEADS + h) * DH * SEQ;

  u32x4 kr0, kr1, vr0, vr1;

#define LOADT(T) { const int tt = (T); const int kt_ = tt & 15;                             \
    const uint16_t* kp = (tt >= 16) ? kbase1 : kbase0;                                      \
    const uint16_t* vp = (tt >= 16) ? vbase1 : vbase0;                                      \
    kr0 = *reinterpret_cast<const u32x4*>(&kp[(size_t)(kt_ * 64 + r0) * DH + c0 * 8]);      \
    kr1 = *reinterpret_cast<const u32x4*>(&kp[(size_t)(kt_ * 64 + r0 + 32) * DH + c0 * 8]); \
    vr0 = *reinterpret_cast<const u32x4*>(&vp[(size_t)r0 * SEQ + kt_ * 64 + c0 * 8]);       \
    vr1 = *reinterpret_cast<const u32x4*>(&vp[(size_t)(r0 + 32) * SEQ + kt_ * 64 + c0 * 8]); }

#define STORET(B) {                                              \
    *reinterpret_cast<u32x4*>(&Klds[B][r0][swc]) = kr0;          \
    *reinterpret_cast<u32x4*>(&Klds[B][r0 + 32][swc]) = kr1;     \
    *reinterpret_cast<u32x4*>(&Vlds[B][r0][swc]) = vr0;          \
    *reinterpret_cast<u32x4*>(&Vlds[B][r0 + 32][swc]) = vr1; }

  LOADT(0);
  STORET(0);
  __syncthreads();

  f32x4 Oacc[4] = {};
  f32x4 Ofin[4] = {};
  float mrow = -1e30f, lrow = 0.f;

  for (int t = 0; t < 32; ++t) {
    const int cur = t & 1;
    if (t < 31) LOADT(t + 1);

    f32x4 S[4];
    __builtin_amdgcn_s_setprio(1);
#pragma unroll
    for (int fn = 0; fn < 4; ++fn) {
      const int krow = klo + 4 * (fn & 1) + 32 * (fn >> 1);
      const int sw = krow & 7;
      bf16x8 ka = *reinterpret_cast<const bf16x8*>(&Klds[cur][krow][8 * (g ^ sw)]);
      bf16x8 kb = *reinterpret_cast<const bf16x8*>(&Klds[cur][krow][8 * ((4 + g) ^ sw)]);
      f32x4 z = {};
      z = __builtin_amdgcn_mfma_f32_16x16x32_bf16(ka, qf0, z, 0, 0, 0);
      S[fn] = __builtin_amdgcn_mfma_f32_16x16x32_bf16(kb, qf1, z, 0, 0, 0);
    }
    __builtin_amdgcn_s_setprio(0);

    float vmax = fmaxf(fmaxf(fmaxf(S[0][0], S[0][1]), fmaxf(S[0][2], S[0][3])),
                       fmaxf(fmaxf(S[1][0], S[1][1]), fmaxf(S[1][2], S[1][3])));
    vmax = fmaxf(vmax, fmaxf(fmaxf(fmaxf(S[2][0], S[2][1]), fmaxf(S[2][2], S[2][3])),
                             fmaxf(fmaxf(S[3][0], S[3][1]), fmaxf(S[3][2], S[3][3]))));
    vmax = fmaxf(vmax, __shfl_xor(vmax, 16));
    vmax = fmaxf(vmax, __shfl_xor(vmax, 32));
    const float mnew = fmaxf(mrow, vmax);
    const float alpha = __expf(mrow - mnew);
    mrow = mnew;
    float rs = 0.f;
#pragma unroll
    for (int fn = 0; fn < 4; ++fn)
#pragma unroll
      for (int i = 0; i < 4; ++i) {
        float p = __expf(S[fn][i] - mnew);
        S[fn][i] = p;
        rs += p;
      }
    rs += __shfl_xor(rs, 16);
    rs += __shfl_xor(rs, 32);
    lrow = lrow * alpha + rs;

    bf16x8 pa0, pa1;
#pragma unroll
    for (int i = 0; i < 4; ++i) {
      pa0[i]     = (__bf16)S[0][i];
      pa0[4 + i] = (__bf16)S[1][i];
      pa1[i]     = (__bf16)S[2][i];
      pa1[4 + i] = (__bf16)S[3][i];
    }

    float af[4];
#pragma unroll
    for (int i = 0; i < 4; ++i) af[i] = __shfl(alpha, 20 * g + i);
#pragma unroll
    for (int fn = 0; fn < 4; ++fn)
#pragma unroll
      for (int i = 0; i < 4; ++i) Oacc[fn][i] *= af[i];

    __builtin_amdgcn_s_setprio(1);
#pragma unroll
    for (int fn = 0; fn < 4; ++fn) {
      const int vrow = fn * 16 + lr;
      const int sw = vrow & 7;
      bf16x8 va = *reinterpret_cast<const bf16x8*>(&Vlds[cur][vrow][8 * (g ^ sw)]);
      bf16x8 vb = *reinterpret_cast<const bf16x8*>(&Vlds[cur][vrow][8 * ((4 + g) ^ sw)]);
      Oacc[fn] = __builtin_amdgcn_mfma_f32_16x16x32_bf16(pa0, va, Oacc[fn], 0, 0, 0);
      Oacc[fn] = __builtin_amdgcn_mfma_f32_16x16x32_bf16(pa1, vb, Oacc[fn], 0, 0, 0);
    }
    __builtin_amdgcn_s_setprio(0);

    if (t == 15 || t == 31) {
      const float linv = 1.f / lrow;
      float li[4];
#pragma unroll
      for (int i = 0; i < 4; ++i) li[i] = __shfl(linv, 20 * g + i);
#pragma unroll
      for (int fn = 0; fn < 4; ++fn)
#pragma unroll
        for (int i = 0; i < 4; ++i) Ofin[fn][i] += Oacc[fn][i] * li[i];
      if (t == 15) {
        mrow = -1e30f; lrow = 0.f;
#pragma unroll
        for (int fn = 0; fn < 4; ++fn) Oacc[fn] = f32x4{};
      }
    }

    if (t < 31) STORET(cur ^ 1);
    __syncthreads();
  }
#undef LOADT
#undef STORET

  uint16_t* o_s = o + (size_t)s * MROWS * DIMC;
#pragma unroll
  for (int fn = 0; fn < 4; ++fn)
#pragma unroll
    for (int i = 0; i < 4; ++i) {
      int n = qt * 64 + w * 16 + g * 4 + i;
      int col = h * 64 + fn * 16 + lr;
      o_s[(size_t)(b * SEQ + n) * DIMC + col] = f2bf(Ofin[fn][i]);
    }
}

// ---------------- projection GEMM v3: 128x64 tile, 2-phase dbuf ----------------
__global__ __launch_bounds__(256) void k_proj_gemm(
    const uint16_t* __restrict__ o, const uint16_t* __restrict__ wpt,
    const float* __restrict__ bp1, const float* __restrict__ bp2,
    float* __restrict__ out) {
  __shared__ __align__(16) uint16_t At[2][128][32];
  __shared__ __align__(16) uint16_t Bt[2][64][32];

  int flat = blockIdx.x + 16 * blockIdx.y + 192 * blockIdx.z;   // 384 blocks
  flat = (flat & 7) * 48 + (flat >> 3);
  const int yb = flat % 12;
  const int xb = (flat / 12) % 16;
  const int s  = flat / 192;
  const int m0 = xb * 128;
  const int col0 = yb * 64;

  const uint16_t* o_s = o + (size_t)s * MROWS * DIMC;
  const uint16_t* w_s = wpt + (size_t)s * DIMC * DIMC;
  const float* bias = (s == 0) ? bp1 : bp2;
  float* out_s = out + (size_t)s * MROWS * DIMC;

  const int tid = threadIdx.x;
  const int w = tid >> 6, lane = tid & 63;
  const int lr = lane & 15, g = lane >> 4;
  const int pc = (g ^ ((lr >> 1) & 3)) * 8;
  const int srow = lane >> 2;
  const int schunk = ((lane & 3) ^ ((lane >> 3) & 3)) * 8;

  f32x4 acc[2][4] = {};

  const size_t aoff0 = (size_t)(m0 + w * 32 + srow) * DIMC + schunk;
  const size_t aoff1 = (size_t)(m0 + w * 32 + 16 + srow) * DIMC + schunk;
  const size_t boff  = (size_t)(col0 + w * 16 + srow) * DIMC + schunk;

#define STAGE(B, K0) do {                                      \
    gl16(o_s + aoff0 + (K0), &At[B][w * 32][0]);               \
    gl16(o_s + aoff1 + (K0), &At[B][w * 32 + 16][0]);          \
    gl16(w_s + boff  + (K0), &Bt[B][w * 16][0]); } while (0)

  STAGE(0, 0);
  asm volatile("s_waitcnt vmcnt(0)" ::: "memory");
  __builtin_amdgcn_s_barrier();

  for (int kt = 0; kt < 24; ++kt) {
    const int cur = kt & 1;
    if (kt < 23) STAGE(cur ^ 1, (kt + 1) * 32);

    bf16x8 a[2], bb[4];
#pragma unroll
    for (int f = 0; f < 2; ++f)
      a[f] = *reinterpret_cast<const bf16x8*>(&At[cur][w * 32 + f * 16 + lr][pc]);
#pragma unroll
    for (int f = 0; f < 4; ++f)
      bb[f] = *reinterpret_cast<const bf16x8*>(&Bt[cur][f * 16 + lr][pc]);

    asm volatile("s_waitcnt lgkmcnt(0)" ::: "memory");
    __builtin_amdgcn_sched_barrier(0);
    __builtin_amdgcn_s_setprio(1);
#pragma unroll
    for (int fm = 0; fm < 2; ++fm)
#pragma unroll
      for (int fn = 0; fn < 4; ++fn)
        acc[fm][fn] = __builtin_amdgcn_mfma_f32_16x16x32_bf16(a[fm], bb[fn], acc[fm][fn], 0, 0, 0);
    __builtin_amdgcn_s_setprio(0);

    asm volatile("s_waitcnt vmcnt(0)" ::: "memory");
    __builtin_amdgcn_s_barrier();
  }
#undef STAGE

#pragma unroll
  for (int fm = 0; fm < 2; ++fm)
#pragma unroll
    for (int fn = 0; fn < 4; ++fn) {
      const int col = col0 + fn * 16 + lr;
      const float bv = bias[col];
#pragma unroll
      for (int i = 0; i < 4; ++i) {
        int m = m0 + w * 32 + fm * 16 + g * 4 + i;
        out_s[(size_t)m * DIMC + col] = acc[fm][fn][i] + bv;
      }
    }
}

extern "C" void kernel_launch(void* const* d_in, const int* in_sizes, int n_in,
                              void* d_out, int out_size, void* d_ws, size_t ws_size,
                              hipStream_t stream) {
  const float* x1    = (const float*)d_in[0];
  const float* x2    = (const float*)d_in[1];
  const float* Wqkv1 = (const float*)d_in[2];
  const float* Wqkv2 = (const float*)d_in[3];
  const float* Wp1   = (const float*)d_in[4];
  const float* bp1   = (const float*)d_in[5];
  const float* Wp2   = (const float*)d_in[6];
  const float* bp2   = (const float*)d_in[7];
  float* out = (float*)d_out;

  uint8_t* ws = (uint8_t*)d_ws;
  uint16_t* xh    = (uint16_t*)(ws);             // 2*2048*768 bf16 = 6291456 B
  uint16_t* xl    = (uint16_t*)(ws + 6291456);
  uint16_t* wqkvt = (uint16_t*)(ws + 12582912);  // 2*2304*768 = 7077888 B
  uint16_t* wpt   = (uint16_t*)(ws + 19660800);  // 2*768*768  = 2359296 B
  uint16_t* qb    = (uint16_t*)(ws + 22020096);  // 2*1572864  = 6291456 B
  uint16_t* kb    = (uint16_t*)(ws + 28311552);
  uint16_t* vtb   = (uint16_t*)(ws + 34603008);
  uint16_t* ob    = (uint16_t*)(ws + 40894464);  // total 47185920 B

  k_split_x<<<3072, 256, 0, stream>>>(x1, x2, xh, xl);
  k_transpose_all<<<4608, dim3(32, 8), 0, stream>>>(Wqkv1, Wqkv2, Wp1, Wp2, wqkvt, wpt);
  k_qkv_gemm<<<dim3(16, 36, 2), 256, 0, stream>>>(xh, xl, wqkvt, qb, kb, vtb);
  k_attn<<<768, 256, 0, stream>>>(qb, kb, vtb, ob);
  k_proj_gemm<<<dim3(16, 12, 2), 256, 0, stream>>>(ob, wpt, bp1, bp2, out);
}